// Round 7
// baseline (357.535 us; speedup 1.0000x reference)
//
#include <hip/hip_runtime.h>

#define M_DIM 16384
#define N_DIM 2048
#define K_DIM 2048
#define KB    (K_DIM / 128)

// GEMM geometry: 256x256 tile, BK=64, 8 waves (2M x 4N); LDS holds A only (64 KiB dbuf)
#define BM 256
#define BN 256
#define BK 64
#define NT (K_DIM / BK)   // 32 K-tiles

// quant grid partition: 256 threads x 8 floats per block
#define XGRID (M_DIM * K_DIM / 2048)   // 16384
#define WGRID (N_DIM * K_DIM / 2048)   // 2048

typedef __bf16 bf16x8 __attribute__((ext_vector_type(8)));
typedef float  f32x4  __attribute__((ext_vector_type(4)));
typedef int    i32x4  __attribute__((ext_vector_type(4)));

__device__ __forceinline__ unsigned short f32_to_bf16_rne(float f) {
    unsigned int u = __float_as_uint(f);
    u += 0x7FFFu + ((u >> 16) & 1u);
    return (unsigned short)(u >> 16);
}

// ---- Fused pass: activation quant+dequant (row-major xdq) and weight dequant ----
// wdq is written in B' FRAGMENT order so the GEMM can load B frags coalesced from global:
//   B'[(n>>6)*32 + (k>>6)][ ((n>>4)&3)*2 + ((k>>5)&1) ][ ((k>>3)&3)*16 + (n&15) ][ k&7 ]
//   (block 4096 elems)     (frag 512 elems)              (lane*8)                 (elem)
__global__ __launch_bounds__(256) void quant_all_kernel(const float* __restrict__ x,
                                                        unsigned short* __restrict__ xdq,
                                                        const float* __restrict__ w,
                                                        const float* __restrict__ wscale,
                                                        unsigned short* __restrict__ wdq) {
    const int tid = threadIdx.x;
    if (blockIdx.x < XGRID) {
        // 16 consecutive lanes cover one 128-elem K-block (8 floats each)
        const size_t base = ((size_t)blockIdx.x * 256 + tid) * 8;
        const float4 va = *(const float4*)(x + base);
        const float4 vb = *(const float4*)(x + base + 4);
        float amax = fmaxf(
            fmaxf(fmaxf(fabsf(va.x), fabsf(va.y)), fmaxf(fabsf(va.z), fabsf(va.w))),
            fmaxf(fmaxf(fabsf(vb.x), fabsf(vb.y)), fmaxf(fabsf(vb.z), fabsf(vb.w))));
#pragma unroll
        for (int m = 8; m >= 1; m >>= 1)
            amax = fmaxf(amax, __shfl_xor(amax, m, 64));
        float s = amax / 448.0f;                  // true f32 div (matches reference)
        if (s == 0.0f) s = 1.0f;
        const int p01 = __builtin_amdgcn_cvt_pk_fp8_f32(va.x / s, va.y / s, 0, false);
        const int p23 = __builtin_amdgcn_cvt_pk_fp8_f32(va.z / s, va.w / s, 0, false);
        const int p45 = __builtin_amdgcn_cvt_pk_fp8_f32(vb.x / s, vb.y / s, 0, false);
        const int p67 = __builtin_amdgcn_cvt_pk_fp8_f32(vb.z / s, vb.w / s, 0, false);
        uint4 out;
        out.x = (unsigned int)f32_to_bf16_rne(__builtin_amdgcn_cvt_f32_fp8(p01, 0) * s)
              | ((unsigned int)f32_to_bf16_rne(__builtin_amdgcn_cvt_f32_fp8(p01, 1) * s) << 16);
        out.y = (unsigned int)f32_to_bf16_rne(__builtin_amdgcn_cvt_f32_fp8(p23, 0) * s)
              | ((unsigned int)f32_to_bf16_rne(__builtin_amdgcn_cvt_f32_fp8(p23, 1) * s) << 16);
        out.z = (unsigned int)f32_to_bf16_rne(__builtin_amdgcn_cvt_f32_fp8(p45, 0) * s)
              | ((unsigned int)f32_to_bf16_rne(__builtin_amdgcn_cvt_f32_fp8(p45, 1) * s) << 16);
        out.w = (unsigned int)f32_to_bf16_rne(__builtin_amdgcn_cvt_f32_fp8(p67, 0) * s)
              | ((unsigned int)f32_to_bf16_rne(__builtin_amdgcn_cvt_f32_fp8(p67, 1) * s) << 16);
        *(uint4*)(xdq + base) = out;
    } else {
        const size_t e = ((size_t)(blockIdx.x - XGRID) * 256 + tid) * 8;
        const float4 va = *(const float4*)(w + e);
        const float4 vb = *(const float4*)(w + e + 4);
        const int n = (int)(e >> 11);
        const int k = (int)(e & 2047);
        const float s = wscale[(n >> 7) * KB + (k >> 7)];   // k..k+7 same 128-block
        uint4 out;
        out.x = (unsigned int)f32_to_bf16_rne(va.x * s) | ((unsigned int)f32_to_bf16_rne(va.y * s) << 16);
        out.y = (unsigned int)f32_to_bf16_rne(va.z * s) | ((unsigned int)f32_to_bf16_rne(va.w * s) << 16);
        out.z = (unsigned int)f32_to_bf16_rne(vb.x * s) | ((unsigned int)f32_to_bf16_rne(vb.y * s) << 16);
        out.w = (unsigned int)f32_to_bf16_rne(vb.z * s) | ((unsigned int)f32_to_bf16_rne(vb.w * s) << 16);
        // B' fragment-order index (ushorts); k..k+7 aligned -> one uint4
        const unsigned idx =
            (((((unsigned)(n >> 6) * 32u + (unsigned)(k >> 6)) * 8u
               + (unsigned)((n >> 4) & 3) * 2u + (unsigned)((k >> 5) & 1)) * 512u)
             + (unsigned)((k >> 3) & 3) * 128u + (unsigned)(n & 15) * 8u);
        *(uint4*)(wdq + idx) = out;
    }
}

// ---- GEMM: C = A @ B^T, bf16 in, f32 out. 256x256 tile; A via LDS (swizzled, dbuf),
//      B direct global->register from fragment-ordered B'; software-pipelined windows ----
//
// Per tile: 4 windows, 16 MFMA each. Window w issues: [4 asm ds_read for window w+1's
// A-frags] [staging gloads / B-frag gloads] [s_waitcnt vmcnt/lgkm counted + sched_barrier]
// [setprio 16 MFMA setprio] [BAR at w1,w3 only].
//   A-reads: w0: ax<-kh0 i4-7; w1: ao<-kh1 i0-3; w2: ax<-kh1 i4-7; w3: ae<-buf^1 kh0 i0-3.
//   lgkm: every window issues 4, waits lgkmcnt(4) (retires previous window's 4).
// VMEM ledger (per wave; issue order per tile: w0: Astg-kh1(t+1) x2, bo01; w1: bo23;
//   w2: Astg-kh0(t+2) x2, be'01; w3: be'23; entering any tile: 6 in flight):
//   w0: 6+4=10, vmcnt(4) retires [Ak0(t+1), be01, be23]  (be needed by ph0 MFMA)
//   w2: 6+4=10, vmcnt(4) retires [Ak1(t+1), bo01, bo23]  (bo needed by ph2 MFMA)
// Barrier safety (2/tile): kh0(t) overwrite (w2 stage) after end-w1 BAR: any wave past it
// has lgkm-retired its kh0 reads (issued w0, waited before ph1-MFMA). kh1(t-1) overwrite
// (w0 stage) after end-w3 BAR: waves past it lgkm-retired their w2-issued kh1 reads.
// Staged-data visibility: Ak0(t+1) retired t-w0-vmcnt, BAR end-w1, first read t-w3;
// Ak1(t+1) retired t-w2-vmcnt, BAR end-w3, first read (t+1)-w1. All ordered.
__global__ __launch_bounds__(512, 2) void gemm_bt_kernel(const unsigned short* __restrict__ A,
                                                         const unsigned short* __restrict__ B,
                                                         float* __restrict__ C) {
    __shared__ __align__(16) unsigned short As[2][2][256][32];   // 64 KiB, A only

    const int tid  = threadIdx.x;
    const int lane = tid & 63;
    const int wave = tid >> 6;
    const int wm   = (wave >> 2) * 128;   // 2 waves along M
    const int wn   = (wave & 3) * 64;     // 4 waves along N
    const int quad = lane >> 4;
    const int l16  = lane & 15;
    const int pc   = quad ^ ((l16 >> 1) & 3);   // physical chunk within a kh-panel

    // grid: x carries M so XCD round-robin partitions A-slabs
    const int m0 = blockIdx.x * BM;
    const int n0 = blockIdx.y * BN;

    f32x4 acc[8][4] = {};

    // A staging: lane row = tid>>2 (0..127), physical chunk tid&3; source pre-swizzled.
    const int srow = tid >> 2;
    const int sc   = (tid & 3) ^ ((tid >> 3) & 3);
    const unsigned short* gA = A + (size_t)(m0 + srow) * K_DIM + sc * 8;

    // B' fragment pointers: block (ng,kt) = 4096 elems; frag(j,kh) at +(j*2+kh)*512;
    // per-lane +lane*8. p01 covers j0-1 (offsets 0/2048/1024/3072 B), p23 covers j2-3.
    const unsigned short* p01 = B + ((size_t)(blockIdx.y * 4 + (wave & 3)) * 32) * 4096 + lane * 8;
    const unsigned short* p23 = p01 + 2048;

#define GLD(SRC, DST) __builtin_amdgcn_global_load_lds( \
    (__attribute__((address_space(1))) void*)(SRC), \
    (__attribute__((address_space(3))) void*)(DST), 16, 0, 0)

#define STG_A(DB, KH, KT) do { \
    GLD(gA + (size_t)(KT) * 64 + (KH) * 32,                       &As[DB][KH][wave * 16][0]); \
    GLD(gA + (size_t)128 * K_DIM + (size_t)(KT) * 64 + (KH) * 32, &As[DB][KH][128 + wave * 16][0]); \
  } while (0)

#define BAR() __builtin_amdgcn_s_barrier()
// Counted waits + compiler scheduling fence (rule-18: MFMA must not hoist above)
#define WAIT2(VN, LN) do { \
    asm volatile("s_waitcnt vmcnt(" #VN ") lgkmcnt(" #LN ")" ::: "memory"); \
    __builtin_amdgcn_sched_barrier(0); \
  } while (0)
#define WAITL(LN) do { \
    asm volatile("s_waitcnt lgkmcnt(" #LN ")" ::: "memory"); \
    __builtin_amdgcn_sched_barrier(0); \
  } while (0)
#define WAITV(VN) do { \
    asm volatile("s_waitcnt vmcnt(" #VN ")" ::: "memory"); \
    __builtin_amdgcn_sched_barrier(0); \
  } while (0)

    // Fragment registers (asm-written, static names only)
    i32x4 ae0, ae1, ae2, ae3;        // A kh-even i0-3
    i32x4 ao0, ao1, ao2, ao3;        // A kh-odd  i0-3
    i32x4 ax0, ax1, ax2, ax3;        // A current i4-7 (time-shared)
    i32x4 be0, be1, be2, be3;        // B kh0 frags j0-3 (global-loaded)
    i32x4 bo0, bo1, bo2, bo3;        // B kh1 frags j0-3

    const unsigned aA = (unsigned)(unsigned long long)
        (__attribute__((address_space(3))) const void*)&As[0][0][wm + l16][pc * 8];

#define DSR(D, IMM) \
    asm volatile("ds_read_b128 %0, %1 offset:%c2" : "=v"(D) : "v"(aA), "i"(IMM))
#define RD_AE(BUF) do { \
    DSR(ae0, (BUF) * 32768 + 0);    DSR(ae1, (BUF) * 32768 + 1024); \
    DSR(ae2, (BUF) * 32768 + 2048); DSR(ae3, (BUF) * 32768 + 3072); \
  } while (0)
#define RD_AO(BUF) do { \
    DSR(ao0, (BUF) * 32768 + 16384 + 0);    DSR(ao1, (BUF) * 32768 + 16384 + 1024); \
    DSR(ao2, (BUF) * 32768 + 16384 + 2048); DSR(ao3, (BUF) * 32768 + 16384 + 3072); \
  } while (0)
#define RD_AX(BUF, KH) do { \
    DSR(ax0, (BUF) * 32768 + (KH) * 16384 + 4096); DSR(ax1, (BUF) * 32768 + (KH) * 16384 + 5120); \
    DSR(ax2, (BUF) * 32768 + (KH) * 16384 + 6144); DSR(ax3, (BUF) * 32768 + (KH) * 16384 + 7168); \
  } while (0)

#define BLD(D, P, OFF) \
    asm volatile("global_load_dwordx4 %0, %1, off offset:%c2" : "=v"(D) : "v"(P), "i"(OFF))

#define BC(X) __builtin_bit_cast(bf16x8, X)
#define MMROW(I, AF, B0, B1, B2, B3) do { \
    acc[I][0] = __builtin_amdgcn_mfma_f32_16x16x32_bf16(BC(AF), BC(B0), acc[I][0], 0, 0, 0); \
    acc[I][1] = __builtin_amdgcn_mfma_f32_16x16x32_bf16(BC(AF), BC(B1), acc[I][1], 0, 0, 0); \
    acc[I][2] = __builtin_amdgcn_mfma_f32_16x16x32_bf16(BC(AF), BC(B2), acc[I][2], 0, 0, 0); \
    acc[I][3] = __builtin_amdgcn_mfma_f32_16x16x32_bf16(BC(AF), BC(B3), acc[I][3], 0, 0, 0); \
  } while (0)
#define MM16(I0, A0, A1, A2, A3, B0, B1, B2, B3) do { \
    __builtin_amdgcn_s_setprio(1); \
    MMROW((I0) + 0, A0, B0, B1, B2, B3); \
    MMROW((I0) + 1, A1, B0, B1, B2, B3); \
    MMROW((I0) + 2, A2, B0, B1, B2, B3); \
    MMROW((I0) + 3, A3, B0, B1, B2, B3); \
    __builtin_amdgcn_s_setprio(0); \
  } while (0)

#define TILE_STD(B_, KT1, KT2) do { \
    RD_AX(B_, 0); STG_A((B_) ^ 1, 1, KT1); BLD(bo0, p01, 1024); BLD(bo1, p01, 3072); \
    WAIT2(4, 4); MM16(0, ae0, ae1, ae2, ae3, be0, be1, be2, be3); \
    RD_AO(B_); BLD(bo2, p23, 1024); BLD(bo3, p23, 3072); \
    WAITL(4); MM16(4, ax0, ax1, ax2, ax3, be0, be1, be2, be3); BAR(); \
    p01 += 4096; p23 += 4096; \
    RD_AX(B_, 1); STG_A(B_, 0, KT2); BLD(be0, p01, 0); BLD(be1, p01, 2048); \
    WAIT2(4, 4); MM16(0, ao0, ao1, ao2, ao3, bo0, bo1, bo2, bo3); \
    RD_AE((B_) ^ 1); BLD(be2, p23, 0); BLD(be3, p23, 2048); \
    WAITL(4); MM16(4, ax0, ax1, ax2, ax3, bo0, bo1, bo2, bo3); BAR(); \
  } while (0)

    // Prologue: A kh0(0), kh1(0) -> buf0; kh0(1) -> buf1 (6 gloads) + be(0) frags (4).
    STG_A(0, 0, 0);
    STG_A(0, 1, 0);
    STG_A(1, 0, 1);
    BLD(be0, p01, 0); BLD(be1, p01, 2048);
    BLD(be2, p23, 0); BLD(be3, p23, 2048);
    WAITV(0);
    BAR();
    RD_AE(0);

#pragma unroll 1
    for (int t = 0; t < NT - 2; t += 2) {
        TILE_STD(0, t + 1, t + 2);
        TILE_STD(1, t + 2, t + 3);
    }
    // Tile 30 (buf0): stage only kh1(31); w2 vmcnt drops to 2 (no Astg issued there).
    RD_AX(0, 0); STG_A(1, 1, NT - 1); BLD(bo0, p01, 1024); BLD(bo1, p01, 3072);
    WAIT2(4, 4); MM16(0, ae0, ae1, ae2, ae3, be0, be1, be2, be3);
    RD_AO(0); BLD(bo2, p23, 1024); BLD(bo3, p23, 3072);
    WAITL(4); MM16(4, ax0, ax1, ax2, ax3, be0, be1, be2, be3); BAR();
    p01 += 4096; p23 += 4096;
    RD_AX(0, 1); BLD(be0, p01, 0); BLD(be1, p01, 2048);
    WAIT2(2, 4); MM16(0, ao0, ao1, ao2, ao3, bo0, bo1, bo2, bo3);
    RD_AE(1); BLD(be2, p23, 0); BLD(be3, p23, 2048);
    WAITL(4); MM16(4, ax0, ax1, ax2, ax3, bo0, bo1, bo2, bo3); BAR();
    // Tile 31 (buf1): no staging; drain B-loads progressively.
    RD_AX(1, 0); BLD(bo0, p01, 1024); BLD(bo1, p01, 3072);
    WAIT2(2, 4); MM16(0, ae0, ae1, ae2, ae3, be0, be1, be2, be3);
    RD_AO(1); BLD(bo2, p23, 1024); BLD(bo3, p23, 3072);
    WAITL(4); MM16(4, ax0, ax1, ax2, ax3, be0, be1, be2, be3); BAR();
    RD_AX(1, 1);
    WAIT2(0, 4); MM16(0, ao0, ao1, ao2, ao3, bo0, bo1, bo2, bo3);
    WAITL(0); MM16(4, ax0, ax1, ax2, ax3, bo0, bo1, bo2, bo3);

    // C/D layout: row = quad*4 + reg, col = lane&15
#pragma unroll
    for (int i = 0; i < 8; ++i) {
        const int row = m0 + wm + i * 16 + quad * 4;
#pragma unroll
        for (int j = 0; j < 4; ++j) {
            const int col = n0 + wn + j * 16 + l16;
            float* cp = C + (size_t)row * N_DIM + col;
#pragma unroll
            for (int r = 0; r < 4; ++r)
                cp[(size_t)r * N_DIM] = acc[i][j][r];
        }
    }
}

extern "C" void kernel_launch(void* const* d_in, const int* in_sizes, int n_in,
                              void* d_out, int out_size, void* d_ws, size_t ws_size,
                              hipStream_t stream) {
    const float* x      = (const float*)d_in[0];
    const float* wfp8   = (const float*)d_in[1];
    const float* wscale = (const float*)d_in[2];
    float* out = (float*)d_out;

    unsigned short* xdq = (unsigned short*)d_ws;                    // M*K bf16 (row-major)
    unsigned short* wdq = xdq + (size_t)M_DIM * K_DIM;              // N*K bf16 (B' frag order)

    quant_all_kernel<<<XGRID + WGRID, 256, 0, stream>>>(x, xdq, wfp8, wscale, wdq);
    gemm_bt_kernel<<<dim3(M_DIM / BM, N_DIM / BN), 512, 0, stream>>>(xdq, wdq, out);
}